// Round 1
// baseline (280.759 us; speedup 1.0000x reference)
//
#include <hip/hip_runtime.h>

// LSTM: B=32768, T=28, D=28(input), H=8(hidden), gates=4H=32, classes=10.
// One thread per batch element. W/b/Wout/bout are wave-uniform -> scalar loads.
// 512 blocks x 64 threads so all 256 CUs are used (2 single-wave blocks/CU).

#define TSTEPS 28
#define DIN    28
#define NH     8
#define NG     32   // 4*NH
#define NC     10

__device__ __forceinline__ float fast_exp2(float x) {
    return __builtin_amdgcn_exp2f(x);
}
__device__ __forceinline__ float fast_rcp(float x) {
    return __builtin_amdgcn_rcpf(x);
}
// sigmoid(z) = 1/(1+e^-z) = rcp(1 + exp2(-z*log2(e)))
__device__ __forceinline__ float fast_sigmoid(float z) {
    return fast_rcp(1.0f + fast_exp2(-1.4426950408889634f * z));
}
// tanh(z) = 1 - 2/(e^{2z}+1) = 1 - 2*rcp(1 + exp2(2z*log2(e)))
__device__ __forceinline__ float fast_tanh(float z) {
    return 1.0f - 2.0f * fast_rcp(1.0f + fast_exp2(2.8853900817779268f * z));
}

__global__ __launch_bounds__(64) void lstm_kernel(
    const float* __restrict__ x,      // [B, T, D]
    const float* __restrict__ W,      // [D+H, 4H]  order i,j,f,o
    const float* __restrict__ bias,   // [4H]
    const float* __restrict__ Wout,   // [H, NC]
    const float* __restrict__ bout,   // [NC]
    float* __restrict__ out,          // [B, NC]
    int B)
{
    const int batch = blockIdx.x * 64 + threadIdx.x;
    if (batch >= B) return;

    const float* xb = x + (size_t)batch * (TSTEPS * DIN);

    float c[NH], h[NH];
#pragma unroll
    for (int u = 0; u < NH; ++u) { c[u] = 0.0f; h[u] = 0.0f; }

    // Prefetch x_0 (28 floats = 7 aligned float4)
    float4 xq[7];
    {
        const float4* xv = (const float4*)xb;
#pragma unroll
        for (int i = 0; i < 7; ++i) xq[i] = xv[i];
    }

#pragma unroll 1
    for (int t = 0; t < TSTEPS; ++t) {
        // Move prefetched x_t to scalar-indexed regs
        float xt[DIN];
#pragma unroll
        for (int i = 0; i < 7; ++i) {
            xt[4*i+0] = xq[i].x; xt[4*i+1] = xq[i].y;
            xt[4*i+2] = xq[i].z; xt[4*i+3] = xq[i].w;
        }
        // Prefetch x_{t+1} to overlap with this step's VALU work
        if (t + 1 < TSTEPS) {
            const float4* xv = (const float4*)(xb + (t + 1) * DIN);
#pragma unroll
            for (int i = 0; i < 7; ++i) xq[i] = xv[i];
        }

        float gates[NG];
#pragma unroll
        for (int g = 0; g < NG; ++g) gates[g] = bias[g];

        // gates += x_t @ W[0:28, :]   (W offsets are compile-time uniform -> s_load)
#pragma unroll
        for (int k = 0; k < DIN; ++k) {
#pragma unroll
            for (int g = 0; g < NG; ++g)
                gates[g] = fmaf(xt[k], W[k * NG + g], gates[g]);
        }
        // gates += h @ W[28:36, :]
#pragma unroll
        for (int k = 0; k < NH; ++k) {
#pragma unroll
            for (int g = 0; g < NG; ++g)
                gates[g] = fmaf(h[k], W[(DIN + k) * NG + g], gates[g]);
        }

        // Cell update, gate order i, j, f, o (BasicLSTMCell), forget bias 1.0
#pragma unroll
        for (int u = 0; u < NH; ++u) {
            float ig = fast_sigmoid(gates[u]);
            float jg = fast_tanh(gates[NH + u]);
            float fg = fast_sigmoid(gates[2 * NH + u] + 1.0f);
            float og = fast_sigmoid(gates[3 * NH + u]);
            float nc = c[u] * fg + ig * jg;
            c[u] = nc;
            h[u] = fast_tanh(nc) * og;
        }
    }

    // logits = h @ Wout + bout
#pragma unroll
    for (int j = 0; j < NC; ++j) {
        float acc = bout[j];
#pragma unroll
        for (int u = 0; u < NH; ++u)
            acc = fmaf(h[u], Wout[u * NC + j], acc);
        out[(size_t)batch * NC + j] = acc;
    }
}

extern "C" void kernel_launch(void* const* d_in, const int* in_sizes, int n_in,
                              void* d_out, int out_size, void* d_ws, size_t ws_size,
                              hipStream_t stream) {
    const float* x    = (const float*)d_in[0];
    const float* W    = (const float*)d_in[1];
    const float* b    = (const float*)d_in[2];
    const float* Wout = (const float*)d_in[3];
    const float* bout = (const float*)d_in[4];
    float* out = (float*)d_out;

    const int B = in_sizes[0] / (TSTEPS * DIN);  // 32768
    const int block = 64;
    const int grid = (B + block - 1) / block;    // 512
    lstm_kernel<<<grid, block, 0, stream>>>(x, W, b, Wout, bout, out, B);
}

// Round 2
// 177.675 us; speedup vs baseline: 1.5802x; 1.5802x over previous
//
#include <hip/hip_runtime.h>

// LSTM: B=32768, T=28, D=28, H=8, gates=32, classes=10.
// 8 lanes per batch element; lane u owns hidden unit u (its i,j,f,o gate
// columns of W live in 144 VGPRs, preloaded once -> zero in-loop W loads).
// h broadcast across the 8-lane group via __shfl each step.
// 1024 blocks x 256 threads = 4096 waves.

#define TSTEPS 28
#define DIN    28
#define NH     8
#define NG     32   // 4*NH
#define NC     10
#define NROWS  36   // DIN + NH

__device__ __forceinline__ float fast_exp2(float x) {
    return __builtin_amdgcn_exp2f(x);
}
__device__ __forceinline__ float fast_rcp(float x) {
    return __builtin_amdgcn_rcpf(x);
}
__device__ __forceinline__ float fast_sigmoid(float z) {
    return fast_rcp(1.0f + fast_exp2(-1.4426950408889634f * z));
}
__device__ __forceinline__ float fast_tanh(float z) {
    return 1.0f - 2.0f * fast_rcp(1.0f + fast_exp2(2.8853900817779268f * z));
}

__global__ __launch_bounds__(256, 2) void lstm_kernel(
    const float* __restrict__ x,      // [B, T, D]
    const float* __restrict__ W,      // [36, 32]  col order i,j,f,o
    const float* __restrict__ bias,   // [32]
    const float* __restrict__ Wout,   // [8, 10]
    const float* __restrict__ bout,   // [10]
    float* __restrict__ out)          // [B, 10]
{
    const int tid  = blockIdx.x * 256 + threadIdx.x;
    const int e    = tid >> 3;            // batch element
    const int u    = tid & 7;             // hidden unit owned by this lane
    const int lane = threadIdx.x & 63;
    const int base8 = lane & ~7;          // first lane of this element's group

    const float* xb = x + (size_t)e * (TSTEPS * DIN);

    // Preload this lane's 4 gate columns of W (rows 0..35) into registers.
    // Full unroll -> compile-time indices -> stays in VGPRs.
    float Wr[NROWS][4];
#pragma unroll
    for (int k = 0; k < NROWS; ++k) {
#pragma unroll
        for (int gt = 0; gt < 4; ++gt)
            Wr[k][gt] = W[k * NG + gt * NH + u];
    }
    float bg[4];
#pragma unroll
    for (int gt = 0; gt < 4; ++gt) bg[gt] = bias[gt * NH + u];

    float c = 0.0f;
    float hall[NH];
#pragma unroll
    for (int j = 0; j < NH; ++j) hall[j] = 0.0f;

    // Prefetch x_0 (28 floats = 7 float4); all 8 lanes of a group read the
    // same addresses -> broadcast-coalesced.
    float4 xq[7];
    {
        const float4* xv = (const float4*)xb;
#pragma unroll
        for (int i = 0; i < 7; ++i) xq[i] = xv[i];
    }

#pragma unroll 1
    for (int t = 0; t < TSTEPS; ++t) {
        float xt[DIN];
#pragma unroll
        for (int i = 0; i < 7; ++i) {
            xt[4*i+0] = xq[i].x; xt[4*i+1] = xq[i].y;
            xt[4*i+2] = xq[i].z; xt[4*i+3] = xq[i].w;
        }
        if (t + 1 < TSTEPS) {
            const float4* xv = (const float4*)(xb + (t + 1) * DIN);
#pragma unroll
            for (int i = 0; i < 7; ++i) xq[i] = xv[i];
        }

        float g[4];
#pragma unroll
        for (int gt = 0; gt < 4; ++gt) g[gt] = bg[gt];

        // x part: 112 FMA, all-register operands
#pragma unroll
        for (int k = 0; k < DIN; ++k) {
#pragma unroll
            for (int gt = 0; gt < 4; ++gt)
                g[gt] = fmaf(xt[k], Wr[k][gt], g[gt]);
        }
        // h part: 32 FMA
#pragma unroll
        for (int k = 0; k < NH; ++k) {
#pragma unroll
            for (int gt = 0; gt < 4; ++gt)
                g[gt] = fmaf(hall[k], Wr[DIN + k][gt], g[gt]);
        }

        // Cell update for this lane's unit (order i, j, f, o; forget bias 1)
        float ig = fast_sigmoid(g[0]);
        float jg = fast_tanh(g[1]);
        float fg = fast_sigmoid(g[2] + 1.0f);
        float og = fast_sigmoid(g[3]);
        c = c * fg + ig * jg;
        float hu = fast_tanh(c) * og;

        // Broadcast all 8 units' h across the group
#pragma unroll
        for (int j = 0; j < NH; ++j)
            hall[j] = __shfl(hu, base8 + j, 64);
    }

    // logits = h @ Wout + bout; lane u writes column u, lanes 0-1 also 8+u
    float acc = bout[u];
#pragma unroll
    for (int k = 0; k < NH; ++k)
        acc = fmaf(hall[k], Wout[k * NC + u], acc);
    out[(size_t)e * NC + u] = acc;

    if (u < 2) {
        float acc1 = bout[NH + u];
#pragma unroll
        for (int k = 0; k < NH; ++k)
            acc1 = fmaf(hall[k], Wout[k * NC + NH + u], acc1);
        out[(size_t)e * NC + NH + u] = acc1;
    }
}

extern "C" void kernel_launch(void* const* d_in, const int* in_sizes, int n_in,
                              void* d_out, int out_size, void* d_ws, size_t ws_size,
                              hipStream_t stream) {
    const float* x    = (const float*)d_in[0];
    const float* W    = (const float*)d_in[1];
    const float* b    = (const float*)d_in[2];
    const float* Wout = (const float*)d_in[3];
    const float* bout = (const float*)d_in[4];
    float* out = (float*)d_out;

    const int B = in_sizes[0] / (TSTEPS * DIN);  // 32768
    const int threads = B * NH;                  // 262144
    const int block = 256;
    const int grid = threads / block;            // 1024
    lstm_kernel<<<grid, block, 0, stream>>>(x, W, b, Wout, bout, out);
}